// Round 8
// baseline (115.141 us; speedup 1.0000x reference)
//
#include <hip/hip_runtime.h>
#include <hip/hip_bf16.h>
#if !__has_builtin(__builtin_amdgcn_cvt_pk_fp8_f32)
#include <hip/hip_fp8.h>
#endif

typedef unsigned char u8;
typedef long long i64;
typedef i64 i64x2 __attribute__((ext_vector_type(2)));
typedef float f32x4 __attribute__((ext_vector_type(4)));

#define NROW 8192
#define NHALF 4096
#define DIM 256
#define TILES 64                       // 8192 / 128
#define NBLK (TILES * (TILES + 1) / 2) // 2080 upper-triangular tiles
#define PBLK 512                       // k_prep blocks (one 16-row strip each)

// gbuf layout (floats): [0..255]=colsum  [256]=ss  [288+s*16]=32 acc slots
#define G_SS 256
#define G_ACC 288
#define G_ZBYTES ((G_ACC + 32 * 16) * 4)

static __device__ __forceinline__ float fast_exp2(float x) {
#if __has_builtin(__builtin_amdgcn_exp2f)
  return __builtin_amdgcn_exp2f(x);
#else
  return exp2f(x);
#endif
}

// pack 4 floats -> 4 OCP e4m3 bytes (RNE, saturating) [k ascending in bytes]
static __device__ __forceinline__ unsigned pack4_fp8(float4 v) {
#if __has_builtin(__builtin_amdgcn_cvt_pk_fp8_f32)
  int p = 0;
  p = __builtin_amdgcn_cvt_pk_fp8_f32(v.x, v.y, p, false); // bytes 0,1
  p = __builtin_amdgcn_cvt_pk_fp8_f32(v.z, v.w, p, true);  // bytes 2,3
  return (unsigned)p;
#else
  __hip_fp8_e4m3 a(v.x), b(v.y), c(v.z), d(v.w);
  return (unsigned)a.__x | ((unsigned)b.__x << 8) | ((unsigned)c.__x << 16) |
         ((unsigned)d.__x << 24);
#endif
}

// Fragment-pair-major fp8 layout: element (row r, col k):
//   strip s=r>>4, pair p=k>>6, half h=(k>>5)&1, quad q=(k&31)>>3, j=k&7
//   byte index = ((s*4+p)*64 + q*16 + (r&15))*16 + h*8 + j
// One wave dwordx4 load at fp=(s*4+p), lane L=q*16+(r&15) yields TWO MFMA A/B
// fragments (chunks 2p, 2p+1): lane holds row s*16+(L&15), k=(L>>4)*8+j.

// ---------------- K1: fp32->fp8 swizzled store + row |x|^2 + atomic partials
__global__ void k_prep(const float* __restrict__ src, const float* __restrict__ tgt,
                       u8* __restrict__ Xq, float* __restrict__ sq,
                       float* __restrict__ gbuf) {
  __shared__ float cps[4][DIM];
  int w = threadIdx.x >> 6, lane = threadIdx.x & 63;
  int s = blockIdx.x;
  int r0 = s * 16 + w * 4;
  // this lane covers k in [4*lane, 4*lane+4)
  int p = lane >> 4, h = (lane >> 3) & 1, q = (lane >> 1) & 3, j = 4 * (lane & 1);
  float4 ca = make_float4(0.f, 0.f, 0.f, 0.f);
  float ssw = 0.f;
#pragma unroll
  for (int rr = 0; rr < 4; ++rr) {
    int row = r0 + rr;
    const float* pp = (row < NHALF) ? (src + (size_t)row * DIM)
                                    : (tgt + (size_t)(row - NHALF) * DIM);
    float4 v = *(const float4*)(pp + lane * 4);
    size_t di = ((size_t)(s * 4 + p) * 64 + q * 16 + (row & 15)) * 16 + h * 8 + j;
    *(unsigned*)(Xq + di) = pack4_fp8(v);
    ca.x += v.x; ca.y += v.y; ca.z += v.z; ca.w += v.w;
    float sum = v.x * v.x + v.y * v.y + v.z * v.z + v.w * v.w;
#pragma unroll
    for (int off = 32; off > 0; off >>= 1) sum += __shfl_down(sum, off);
    if (lane == 0) { sq[row] = sum; ssw += sum; }
  }
  if (lane == 0) atomicAdd(gbuf + G_SS, ssw); // 4 atomics/block
  cps[w][lane * 4 + 0] = ca.x;
  cps[w][lane * 4 + 1] = ca.y;
  cps[w][lane * 4 + 2] = ca.z;
  cps[w][lane * 4 + 3] = ca.w;
  __syncthreads();
  int cc = threadIdx.x;
  atomicAdd(gbuf + cc, cps[0][cc] + cps[1][cc] + cps[2][cc] + cps[3][cc]);
}

// ---------------- K2: fused fp8 X*X^T + multi-RBF epilogue + signed reduce --
// 2080 blocks (upper-tri 128x128 tiles) x 256 threads (4 waves, 2x2 of 64x64).
// Round-5 structure (best known): no LDS staging, no K-loop barriers, fully
// unrolled p-loop so the compiler pipelines all 32 dwordx4 loads against the
// 128 MFMAs; fp8 fragments keep regs <=128 -> 4 blocks/CU.
// Bandwidth scalar computed per-block from colsum partials (no k_scal pass).
__global__ __launch_bounds__(256, 4) void k_main(const u8* __restrict__ Xq,
                                                 const float* __restrict__ sq,
                                                 const float* __restrict__ gbuf,
                                                 float* __restrict__ accbuf) {
  __shared__ float red[4];
  __shared__ float c4sh;

  int tid = threadIdx.x;
  int w = tid >> 6, lane = tid & 63;

  // ---- per-block bandwidth scalar: c4 = log2(e)/(16*bw) ----
  {
    float v = gbuf[tid]; // colsum_c
    float vn = v * v;
#pragma unroll
    for (int off = 32; off > 0; off >>= 1) vn += __shfl_down(vn, off);
    if (lane == 0) red[w] = vn;
    __syncthreads();
    if (tid == 0) {
      double VN = (double)red[0] + red[1] + red[2] + red[3];
      double S  = (double)gbuf[G_SS];
      double suml2 = 2.0 * (double)NROW * S - 2.0 * VN;
      double bw = suml2 / ((double)NROW * NROW - NROW) / 4.0; // / 2^(KN/2)
      c4sh = (float)(1.4426950408889634 / (bw * 16.0));
    }
    __syncthreads();
  }

  // linear triangle index -> (bi, bj), bj >= bi
  int bi = 0, rem = blockIdx.x;
  while (rem >= TILES - bi) { rem -= TILES - bi; ++bi; }
  int bj = bi + rem;

  int wi = w >> 1, wj = w & 1;

  f32x4 acc[4][4];
#pragma unroll
  for (int a = 0; a < 4; ++a)
#pragma unroll
    for (int b = 0; b < 4; ++b) acc[a][b] = (f32x4){0.f, 0.f, 0.f, 0.f};

  const i64x2* X2 = (const i64x2*)Xq; // fragment-pair fp: X2[fp*64 + lane]
  const int sA = bi * 8 + wi * 4;     // this wave's 4 A-strips
  const int sB = bj * 8 + wj * 4;     // this wave's 4 B-strips

  // Hoist epilogue inputs for extra MLP while MFMAs run.
  int ib = bi * 128 + wi * 64 + (lane >> 4) * 4;
  int jb = bj * 128 + wj * 64 + (lane & 15);
  f32x4 sqi[4];
#pragma unroll
  for (int mi = 0; mi < 4; ++mi) sqi[mi] = *(const f32x4*)(sq + ib + mi * 16);
  float sqjv[4];
#pragma unroll
  for (int ni = 0; ni < 4; ++ni) sqjv[ni] = sq[jb + ni * 16];

#pragma unroll
  for (int p = 0; p < 4; ++p) {
    i64x2 aP[4], bP[4];
#pragma unroll
    for (int mi = 0; mi < 4; ++mi)
      aP[mi] = X2[(size_t)((sA + mi) * 4 + p) * 64 + lane];
#pragma unroll
    for (int ni = 0; ni < 4; ++ni)
      bP[ni] = X2[(size_t)((sB + ni) * 4 + p) * 64 + lane];
#pragma unroll
    for (int mi = 0; mi < 4; ++mi)
#pragma unroll
      for (int ni = 0; ni < 4; ++ni)
        acc[mi][ni] = __builtin_amdgcn_mfma_f32_16x16x32_fp8_fp8(
            aP[mi].x, bP[ni].x, acc[mi][ni], 0, 0, 0);
#pragma unroll
    for (int mi = 0; mi < 4; ++mi)
#pragma unroll
      for (int ni = 0; ni < 4; ++ni)
        acc[mi][ni] = __builtin_amdgcn_mfma_f32_16x16x32_fp8_fp8(
            aP[mi].y, bP[ni].y, acc[mi][ni], 0, 0, 0);
  }

  // Epilogue: l2 -> t + t^2 + t^4 + t^8 + t^16, signed sum.
  // C/D layout: col = lane&15, row = (lane>>4)*4 + reg (dtype-independent).
  float c4 = c4sh;
  float wgt = ((bi < 32) == (bj < 32)) ? 1.f : -1.f; // quadrant sign s_i*s_j
  if (bi != bj) wgt *= 2.f;                          // symmetry: count (j,i) too
  bool diag = (bi == bj);
  float lsum = 0.f;
#pragma unroll
  for (int ni = 0; ni < 4; ++ni) {
    float sqj = sqjv[ni];
#pragma unroll
    for (int mi = 0; mi < 4; ++mi) {
#pragma unroll
      for (int r = 0; r < 4; ++r) {
        float l2 = sqi[mi][r] + sqj - 2.f * acc[mi][ni][r];
        float t  = fast_exp2(-l2 * c4);
        float t2 = t * t, t4 = t2 * t2, t8 = t4 * t4, t16 = t8 * t8;
        float tt = t + t2 + t4 + t8 + t16;
        // exact diagonal: K_ii = 5 (kills fp8 quantization bias on l2_ii)
        if (diag && (ib + mi * 16 + r) == (jb + ni * 16)) tt = 5.f;
        lsum += tt;
      }
    }
  }
#pragma unroll
  for (int off = 32; off > 0; off >>= 1) lsum += __shfl_down(lsum, off);
  if (lane == 0) red[w] = lsum;
  __syncthreads();
  if (tid == 0)
    atomicAdd(accbuf + (blockIdx.x & 31) * 16,
              wgt * (red[0] + red[1] + red[2] + red[3]));
}

// ---------------- K3: finalize ----------------------------------------------
__global__ void k_fin(const float* __restrict__ accbuf, float* __restrict__ out) {
  int lane = threadIdx.x & 63;
  float s = (lane < 32) ? accbuf[lane * 16] : 0.f;
#pragma unroll
  for (int off = 32; off > 0; off >>= 1) s += __shfl_down(s, off);
  if (threadIdx.x == 0) out[0] = s / 16777216.f; // / 4096^2
}

extern "C" void kernel_launch(void* const* d_in, const int* in_sizes, int n_in,
                              void* d_out, int out_size, void* d_ws, size_t ws_size,
                              hipStream_t stream) {
  const float* src = (const float*)d_in[0];
  const float* tgt = (const float*)d_in[1];
  char* ws = (char*)d_ws;
  u8* Xq = (u8*)ws;                                  // 2 MiB swizzled fp8
  size_t off = (size_t)NROW * DIM;
  float* sq = (float*)(ws + off);   off += NROW * 4; // 32 KiB row |x|^2
  float* gbuf = (float*)(ws + off);                  // colsum/ss/acc slots
  float* out = (float*)d_out;

  hipMemsetAsync(gbuf, 0, G_ZBYTES, stream);
  k_prep<<<PBLK, 256, 0, stream>>>(src, tgt, Xq, sq, gbuf);
  k_main<<<NBLK, 256, 0, stream>>>(Xq, sq, gbuf, gbuf + G_ACC);
  k_fin<<<1, 64, 0, stream>>>(gbuf + G_ACC, out);
}

// Round 9
// 89.320 us; speedup vs baseline: 1.2891x; 1.2891x over previous
//
#include <hip/hip_runtime.h>
#include <hip/hip_bf16.h>
#if !__has_builtin(__builtin_amdgcn_cvt_pk_fp8_f32)
#include <hip/hip_fp8.h>
#endif

typedef unsigned char u8;
typedef unsigned short u16;
typedef long long i64;
typedef i64 i64x2 __attribute__((ext_vector_type(2)));
typedef float f32x4 __attribute__((ext_vector_type(4)));

#define NROW 8192
#define NHALF 4096
#define DIM 256
#define TILES 64                       // 8192 / 128
#define NBLK (TILES * (TILES + 1) / 2) // 2080 upper-triangular tiles
#define PBLK 512                       // k_prep blocks (one 16-row strip each)

static __device__ __forceinline__ float fast_exp2(float x) {
#if __has_builtin(__builtin_amdgcn_exp2f)
  return __builtin_amdgcn_exp2f(x);
#else
  return exp2f(x);
#endif
}

// pack 4 floats -> 4 OCP e4m3 bytes (RNE, saturating) [k ascending in bytes]
static __device__ __forceinline__ unsigned pack4_fp8(float4 v) {
#if __has_builtin(__builtin_amdgcn_cvt_pk_fp8_f32)
  int p = 0;
  p = __builtin_amdgcn_cvt_pk_fp8_f32(v.x, v.y, p, false); // bytes 0,1
  p = __builtin_amdgcn_cvt_pk_fp8_f32(v.z, v.w, p, true);  // bytes 2,3
  return (unsigned)p;
#else
  __hip_fp8_e4m3 a(v.x), b(v.y), c(v.z), d(v.w);
  return (unsigned)a.__x | ((unsigned)b.__x << 8) | ((unsigned)c.__x << 16) |
         ((unsigned)d.__x << 24);
#endif
}

// Fragment-pair-major fp8 layout: element (row r, col k):
//   strip s=r>>4, pair p=k>>6, half h=(k>>5)&1, quad q=(k&31)>>3, j=k&7
//   byte index = ((s*4+p)*64 + q*16 + (r&15))*16 + h*8 + j
// One wave dwordx4 load at fp=(s*4+p), lane L=q*16+(r&15) yields TWO MFMA A/B
// fragments (chunks 2p, 2p+1): lane holds row s*16+(L&15), k=(L>>4)*8+j.

// ---------------- K1: fp32->fp8 swizzled store + row |x|^2 + col partials ---
__global__ void k_prep(const float* __restrict__ src, const float* __restrict__ tgt,
                       u8* __restrict__ Xq, float* __restrict__ sq,
                       float* __restrict__ colpart) {
  __shared__ float cps[4][DIM];
  int w = threadIdx.x >> 6, lane = threadIdx.x & 63;
  int s = blockIdx.x;
  int r0 = s * 16 + w * 4;
  // this lane covers k in [4*lane, 4*lane+4)
  int p = lane >> 4, h = (lane >> 3) & 1, q = (lane >> 1) & 3, j = 4 * (lane & 1);
  float4 ca = make_float4(0.f, 0.f, 0.f, 0.f);
#pragma unroll
  for (int rr = 0; rr < 4; ++rr) {
    int row = r0 + rr;
    const float* pp = (row < NHALF) ? (src + (size_t)row * DIM)
                                    : (tgt + (size_t)(row - NHALF) * DIM);
    float4 v = *(const float4*)(pp + lane * 4);
    size_t di = ((size_t)(s * 4 + p) * 64 + q * 16 + (row & 15)) * 16 + h * 8 + j;
    *(unsigned*)(Xq + di) = pack4_fp8(v);
    ca.x += v.x; ca.y += v.y; ca.z += v.z; ca.w += v.w;
    float sum = v.x * v.x + v.y * v.y + v.z * v.z + v.w * v.w;
#pragma unroll
    for (int off = 32; off > 0; off >>= 1) sum += __shfl_down(sum, off);
    if (lane == 0) sq[row] = sum;
  }
  cps[w][lane * 4 + 0] = ca.x;
  cps[w][lane * 4 + 1] = ca.y;
  cps[w][lane * 4 + 2] = ca.z;
  cps[w][lane * 4 + 3] = ca.w;
  __syncthreads();
  int cc = threadIdx.x;
  colpart[blockIdx.x * DIM + cc] = cps[0][cc] + cps[1][cc] + cps[2][cc] + cps[3][cc];
}

// ---------------- K1b: fold 512 col-partials -> 32 ---------------------------
__global__ void k_red(const float* __restrict__ colpart, float* __restrict__ colpart2) {
  int b = blockIdx.x, c = threadIdx.x; // 32 blocks x 256 threads
  float s = 0.f;
#pragma unroll
  for (int i = 0; i < 16; ++i) s += colpart[(size_t)(b * 16 + i) * DIM + c];
  colpart2[b * DIM + c] = s;
}

// ---------------- K2: bandwidth scalar + zero the 32 accumulator slots ------
__global__ void k_scal(const float* __restrict__ sq, const float* __restrict__ colpart2,
                       float* __restrict__ scal) {
  int c = threadIdx.x, lane = c & 63, w = c >> 6;
  float vs = 0.f;
#pragma unroll
  for (int b = 0; b < 32; ++b) vs += colpart2[b * DIM + c];
  float vn = vs * vs;
  float ss = 0.f;
#pragma unroll
  for (int k = 0; k < NROW / DIM; ++k) ss += sq[k * DIM + c];
#pragma unroll
  for (int off = 32; off > 0; off >>= 1) {
    vn += __shfl_down(vn, off);
    ss += __shfl_down(ss, off);
  }
  __shared__ float rv[4], rs[4];
  if (lane == 0) { rv[w] = vn; rs[w] = ss; }
  __syncthreads();
  if (c == 0) {
    double S  = (double)rs[0] + rs[1] + rs[2] + rs[3];
    double VN = (double)rv[0] + rv[1] + rv[2] + rv[3];
    double suml2 = 2.0 * (double)NROW * S - 2.0 * VN;
    double bw = suml2 / ((double)NROW * NROW - NROW) / 4.0; // / KERNEL_MUL^(5/2)
    scal[0] = (float)(1.4426950408889634 / (bw * 16.0)); // t = exp2(-l2*scal0)
  }
  if (c < 32) scal[16 + c * 16] = 0.f; // 32 accumulator slots, 64B apart
}

// ---------------- K3: fused fp8 X*X^T + multi-RBF epilogue + signed reduce --
// 2080 blocks (upper-tri 128x128 tiles) x 256 threads (4 waves, 2x2 of 64x64).
// No LDS staging, no K-loop barriers; fp8 halves bytes AND fragment registers
// vs bf16 -> <=128 regs/wave -> 4 blocks/CU (launch_bounds-enforced).
__global__ __launch_bounds__(256, 4) void k_main(const u8* __restrict__ Xq,
                                                 const float* __restrict__ sq,
                                                 const float* __restrict__ scal,
                                                 float* __restrict__ accbuf) {
  __shared__ float red[4];

  // linear triangle index -> (bi, bj), bj >= bi
  int bi = 0, rem = blockIdx.x;
  while (rem >= TILES - bi) { rem -= TILES - bi; ++bi; }
  int bj = bi + rem;

  int tid = threadIdx.x;
  int w = tid >> 6, lane = tid & 63;
  int wi = w >> 1, wj = w & 1;

  f32x4 acc[4][4];
#pragma unroll
  for (int a = 0; a < 4; ++a)
#pragma unroll
    for (int b = 0; b < 4; ++b) acc[a][b] = (f32x4){0.f, 0.f, 0.f, 0.f};

  const i64x2* X2 = (const i64x2*)Xq; // fragment-pair fp: X2[fp*64 + lane]
  const int sA = bi * 8 + wi * 4;     // this wave's 4 A-strips
  const int sB = bj * 8 + wj * 4;     // this wave's 4 B-strips

#pragma unroll
  for (int p = 0; p < 4; ++p) {
    i64x2 aP[4], bP[4];
#pragma unroll
    for (int mi = 0; mi < 4; ++mi)
      aP[mi] = X2[(size_t)((sA + mi) * 4 + p) * 64 + lane];
#pragma unroll
    for (int ni = 0; ni < 4; ++ni)
      bP[ni] = X2[(size_t)((sB + ni) * 4 + p) * 64 + lane];
#pragma unroll
    for (int mi = 0; mi < 4; ++mi)
#pragma unroll
      for (int ni = 0; ni < 4; ++ni)
        acc[mi][ni] = __builtin_amdgcn_mfma_f32_16x16x32_fp8_fp8(
            aP[mi].x, bP[ni].x, acc[mi][ni], 0, 0, 0);
#pragma unroll
    for (int mi = 0; mi < 4; ++mi)
#pragma unroll
      for (int ni = 0; ni < 4; ++ni)
        acc[mi][ni] = __builtin_amdgcn_mfma_f32_16x16x32_fp8_fp8(
            aP[mi].y, bP[ni].y, acc[mi][ni], 0, 0, 0);
  }

  // Epilogue: l2 -> t + t^2 + t^4 + t^8 + t^16, signed sum.
  // C/D layout: col = lane&15, row = (lane>>4)*4 + reg (dtype-independent).
  float c4 = scal[0];
  float wgt = ((bi < 32) == (bj < 32)) ? 1.f : -1.f; // quadrant sign s_i*s_j
  if (bi != bj) wgt *= 2.f;                          // symmetry: count (j,i) too
  bool diag = (bi == bj);
  int ib = bi * 128 + wi * 64 + (lane >> 4) * 4;
  int jb = bj * 128 + wj * 64 + (lane & 15);
  f32x4 sqi[4];
#pragma unroll
  for (int mi = 0; mi < 4; ++mi) sqi[mi] = *(const f32x4*)(sq + ib + mi * 16);
  float lsum = 0.f;
#pragma unroll
  for (int ni = 0; ni < 4; ++ni) {
    float sqj = sq[jb + ni * 16];
#pragma unroll
    for (int mi = 0; mi < 4; ++mi) {
#pragma unroll
      for (int r = 0; r < 4; ++r) {
        float l2 = sqi[mi][r] + sqj - 2.f * acc[mi][ni][r];
        float t  = fast_exp2(-l2 * c4);
        float t2 = t * t, t4 = t2 * t2, t8 = t4 * t4, t16 = t8 * t8;
        float tt = t + t2 + t4 + t8 + t16;
        // exact diagonal: K_ii = 5 (kills fp8 quantization bias on l2_ii)
        if (diag && (ib + mi * 16 + r) == (jb + ni * 16)) tt = 5.f;
        lsum += tt;
      }
    }
  }
#pragma unroll
  for (int off = 32; off > 0; off >>= 1) lsum += __shfl_down(lsum, off);
  if (lane == 0) red[w] = lsum;
  __syncthreads();
  if (tid == 0)
    atomicAdd(accbuf + (blockIdx.x & 31) * 16,
              wgt * (red[0] + red[1] + red[2] + red[3]));
}

// ---------------- K4: finalize ----------------------------------------------
__global__ void k_fin(const float* __restrict__ accbuf, float* __restrict__ out) {
  int lane = threadIdx.x & 63;
  float s = (lane < 32) ? accbuf[lane * 16] : 0.f;
#pragma unroll
  for (int off = 32; off > 0; off >>= 1) s += __shfl_down(s, off);
  if (threadIdx.x == 0) out[0] = s / 16777216.f; // / 4096^2
}

extern "C" void kernel_launch(void* const* d_in, const int* in_sizes, int n_in,
                              void* d_out, int out_size, void* d_ws, size_t ws_size,
                              hipStream_t stream) {
  const float* src = (const float*)d_in[0];
  const float* tgt = (const float*)d_in[1];
  char* ws = (char*)d_ws;
  u8* Xq = (u8*)ws;                                        // 2 MiB swizzled fp8
  size_t off = (size_t)NROW * DIM;
  float* sq = (float*)(ws + off);        off += NROW * 4;  // 32 KiB row |x|^2
  float* colpart = (float*)(ws + off);   off += (size_t)PBLK * DIM * 4; // 512 KiB
  float* colpart2 = (float*)(ws + off);  off += (size_t)32 * DIM * 4;   // 32 KiB
  float* scal = (float*)(ws + off);      // [0]=c4; [16 + s*16] = 32 acc slots
  float* out = (float*)d_out;

  k_prep<<<PBLK, 256, 0, stream>>>(src, tgt, Xq, sq, colpart);
  k_red<<<32, 256, 0, stream>>>(colpart, colpart2);
  k_scal<<<1, 256, 0, stream>>>(sq, colpart2, scal);
  k_main<<<NBLK, 256, 0, stream>>>(Xq, sq, scal, scal + 16);
  k_fin<<<1, 64, 0, stream>>>(scal + 16, out);
}